// Round 2
// baseline (794.536 us; speedup 1.0000x reference)
//
#include <hip/hip_runtime.h>
#include <math.h>

#define BB 32
#define TT 2048
#define FF 512
#define UU 512

// ws layout (floats):
// hw:     [0,      16384)
// alpha:  [16384,  81920)
// scores: [81920,  147456)   -- zeroed each call (atomic accum target)
// c:      [147456, 163840)   -- zeroed each call (atomic accum target)

__global__ __launch_bounds__(256) void k1_hw(
    const float* __restrict__ h, const float* __restrict__ Wa,
    const float* __restrict__ Wa_bias, const float* __restrict__ Ua_bias,
    float* __restrict__ hw) {
  int idx = blockIdx.x * blockDim.x + threadIdx.x;  // 16384 = B*U
  int b = idx >> 9;
  int u = idx & 511;
  float acc = Wa_bias[u] + Ua_bias[u];
  const float* hrow = h + b * UU;
  for (int f = 0; f < UU; ++f) acc += hrow[f] * Wa[f * UU + u];
  hw[idx] = acc;
}

// scores partial: block computes 64(t) x 64(u) tile of ann@Ua (K=512),
// then tanh(+hw)*Va row-reduce, atomicAdd into scores[b][t].
__global__ __launch_bounds__(256) void k2_scores(
    const float* __restrict__ ann, const float* __restrict__ Ua,
    const float* __restrict__ Va, const float* __restrict__ hw,
    float* __restrict__ scores) {
  __shared__ float As[64][65];
  __shared__ float Bs[64][65];
  const int b = blockIdx.z;
  const int t0 = blockIdx.x * 64;
  const int u0 = blockIdx.y * 64;
  const int tid = threadIdx.x;
  const int ty = tid >> 4;   // 0..15
  const int tx = tid & 15;   // 0..15

  float acc[4][4];
#pragma unroll
  for (int a = 0; a < 4; ++a)
#pragma unroll
    for (int q = 0; q < 4; ++q) acc[a][q] = 0.f;

  const float* annb = ann + (size_t)b * TT * FF;

  for (int k0 = 0; k0 < FF; k0 += 64) {
#pragma unroll
    for (int r = 0; r < 4; ++r) {
      int i = ty + r * 16;          // row 0..63
      int k = tx * 4;               // col 0..63 step 4
      const float4 v = *reinterpret_cast<const float4*>(
          annb + (size_t)(t0 + i) * FF + k0 + k);
      As[i][k] = v.x; As[i][k + 1] = v.y; As[i][k + 2] = v.z; As[i][k + 3] = v.w;
      const float4 w = *reinterpret_cast<const float4*>(
          Ua + (size_t)(k0 + i) * UU + u0 + k);
      Bs[i][k] = w.x; Bs[i][k + 1] = w.y; Bs[i][k + 2] = w.z; Bs[i][k + 3] = w.w;
    }
    __syncthreads();
#pragma unroll
    for (int k = 0; k < 64; ++k) {
      float av[4], bv[4];
#pragma unroll
      for (int a = 0; a < 4; ++a) av[a] = As[ty + 16 * a][k];
#pragma unroll
      for (int q = 0; q < 4; ++q) bv[q] = Bs[k][tx + 16 * q];
#pragma unroll
      for (int a = 0; a < 4; ++a)
#pragma unroll
        for (int q = 0; q < 4; ++q) acc[a][q] += av[a] * bv[q];
    }
    __syncthreads();
  }

  // epilogue: tanh(acc + hw[b][j]) * Va[j], reduce over j
  float part[4];
#pragma unroll
  for (int a = 0; a < 4; ++a) {
    float s = 0.f;
#pragma unroll
    for (int q = 0; q < 4; ++q) {
      int j = u0 + tx + 16 * q;
      s += tanhf(acc[a][q] + hw[b * UU + j]) * Va[j];
    }
    part[a] = s;
  }
  float* red = &As[0][0];  // reuse LDS (safe: sync'd above)
#pragma unroll
  for (int a = 0; a < 4; ++a) red[(ty + 16 * a) * 16 + tx] = part[a];
  __syncthreads();
  if (tid < 64) {
    float s = 0.f;
#pragma unroll
    for (int j = 0; j < 16; ++j) s += red[tid * 16 + j];
    atomicAdd(&scores[b * TT + t0 + tid], s);
  }
}

__global__ __launch_bounds__(256) void k3_softmax(
    const float* __restrict__ scores, float* __restrict__ alpha) {
  const int b = blockIdx.x;
  const int tid = threadIdx.x;
  __shared__ float red[256];
  float v[8];
  float m = -1e30f;
#pragma unroll
  for (int i = 0; i < 8; ++i) {
    v[i] = scores[b * TT + tid + i * 256];
    m = fmaxf(m, v[i]);
  }
  red[tid] = m;
  __syncthreads();
  for (int s = 128; s > 0; s >>= 1) {
    if (tid < s) red[tid] = fmaxf(red[tid], red[tid + s]);
    __syncthreads();
  }
  m = red[0];
  __syncthreads();
  float sum = 0.f;
#pragma unroll
  for (int i = 0; i < 8; ++i) {
    v[i] = expf(v[i] - m);
    sum += v[i];
  }
  red[tid] = sum;
  __syncthreads();
  for (int s = 128; s > 0; s >>= 1) {
    if (tid < s) red[tid] += red[tid + s];
    __syncthreads();
  }
  float inv = 1.f / red[0];
#pragma unroll
  for (int i = 0; i < 8; ++i) alpha[b * TT + tid + i * 256] = v[i] * inv;
}

__global__ __launch_bounds__(256) void k4_context(
    const float* __restrict__ ann, const float* __restrict__ alpha,
    float* __restrict__ c) {
  const int b = blockIdx.y;
  const int t0 = blockIdx.x * 64;
  const int tid = threadIdx.x;
  float2 acc = {0.f, 0.f};
  const float* base = ann + (size_t)b * TT * FF;
  for (int tt = 0; tt < 64; ++tt) {
    int t = t0 + tt;
    float a = alpha[b * TT + t];
    const float2 v = *reinterpret_cast<const float2*>(base + (size_t)t * FF + tid * 2);
    acc.x += a * v.x;
    acc.y += a * v.y;
  }
  atomicAdd(&c[b * FF + tid * 2], acc.x);
  atomicAdd(&c[b * FF + tid * 2 + 1], acc.y);
}

// One block per batch row. 512 threads, one per output u.
// Phase 1: z, r (6 dots). Phase 2: hh needs (r*h) @ rk_h  -- note the
// reference's `r * h @ rk` parses as (r*h)@rk (left-assoc, equal precedence).
__global__ __launch_bounds__(512) void k5_cell(
    const float* __restrict__ x, const float* __restrict__ h,
    const float* __restrict__ c, const float* __restrict__ kern,
    const float* __restrict__ rk, const float* __restrict__ ak,
    const float* __restrict__ bias, const float* __restrict__ abias,
    float* __restrict__ out) {
  const int b = blockIdx.x;
  const int u = threadIdx.x;  // 0..511
  __shared__ float xs[512], cs[512], hs[512], rhs[512];
  xs[u] = x[b * FF + u];
  cs[u] = c[b * FF + u];
  hs[u] = h[b * UU + u];
  __syncthreads();

  float xz = bias[u], xr = bias[u + UU], xh = bias[u + 2 * UU];
  float az = abias[u], ar = abias[u + UU], ah = abias[u + 2 * UU];
  float hz = 0.f, hr = 0.f;
  for (int f = 0; f < FF; ++f) {
    float xv = xs[f], cv = cs[f], hv = hs[f];
    const float* kf = kern + (size_t)f * 3 * UU;
    const float* af = ak + (size_t)f * 3 * UU;
    const float* rf = rk + (size_t)f * 3 * UU;
    xz += xv * kf[u]; xr += xv * kf[u + UU]; xh += xv * kf[u + 2 * UU];
    az += cv * af[u]; ar += cv * af[u + UU]; ah += cv * af[u + 2 * UU];
    hz += hv * rf[u]; hr += hv * rf[u + UU];
  }
  float z = fminf(fmaxf(0.2f * (xz + hz + az) + 0.5f, 0.f), 1.f);
  float r = fminf(fmaxf(0.2f * (xr + hr + ar) + 0.5f, 0.f), 1.f);
  rhs[u] = r * hs[u];
  __syncthreads();

  float q = 0.f;
  for (int f = 0; f < FF; ++f) q += rhs[f] * rk[(size_t)f * 3 * UU + 2 * UU + u];
  float hh = tanhf(xh + q + ah);
  out[b * UU + u] = z * hs[u] + (1.f - z) * hh;
}

extern "C" void kernel_launch(void* const* d_in, const int* in_sizes, int n_in,
                              void* d_out, int out_size, void* d_ws, size_t ws_size,
                              hipStream_t stream) {
  const float* x       = (const float*)d_in[0];
  const float* h       = (const float*)d_in[1];
  const float* ann     = (const float*)d_in[2];
  const float* kern    = (const float*)d_in[3];
  const float* rk      = (const float*)d_in[4];
  const float* ak      = (const float*)d_in[5];
  const float* Wa      = (const float*)d_in[6];
  const float* Ua      = (const float*)d_in[7];
  const float* Va      = (const float*)d_in[8];
  const float* bias    = (const float*)d_in[9];
  const float* abias   = (const float*)d_in[10];
  const float* Wa_bias = (const float*)d_in[11];
  const float* Ua_bias = (const float*)d_in[12];

  float* ws     = (float*)d_ws;
  float* hw     = ws;            // 16384
  float* alpha  = ws + 16384;    // 65536
  float* scores = ws + 81920;    // 65536
  float* c      = ws + 147456;   // 16384

  // zero the atomic-accumulation targets (scores + c are contiguous)
  hipMemsetAsync(scores, 0, (65536 + 16384) * sizeof(float), stream);

  k1_hw<<<64, 256, 0, stream>>>(h, Wa, Wa_bias, Ua_bias, hw);

  dim3 g2(TT / 64, UU / 64, BB);
  k2_scores<<<g2, 256, 0, stream>>>(ann, Ua, Va, hw, scores);

  k3_softmax<<<BB, 256, 0, stream>>>(scores, alpha);

  dim3 g4(TT / 64, BB);
  k4_context<<<g4, 256, 0, stream>>>(ann, alpha, c);

  k5_cell<<<BB, 512, 0, stream>>>(x, h, c, kern, rk, ak, bias, abias,
                                  (float*)d_out);
}

// Round 3
// 233.727 us; speedup vs baseline: 3.3994x; 3.3994x over previous
//
#include <hip/hip_runtime.h>
#include <hip/hip_bf16.h>
#include <math.h>

#define BB 32
#define TT 2048
#define FF 512
#define UU 512

typedef __attribute__((ext_vector_type(4))) float f32x4;
typedef __attribute__((ext_vector_type(4))) short bf16x4;
typedef __attribute__((ext_vector_type(8))) short bf16x8;

__device__ inline short f2bf(float f) {
  union { __hip_bfloat16 h; short s; } u;
  u.h = __float2bfloat16(f);
  return u.s;
}

// ws layout (floats):
// hw:     [0,      16384)
// alpha:  [16384,  81920)
// scores: [81920,  147456)   -- written directly by k2 (no atomics)
// c:      [147456, 163840)   -- zeroed each call (atomic accum target)
// Up:     shorts at float-offset 163840, 262144 shorts (512KB)

__global__ __launch_bounds__(256) void k1_hw(
    const float* __restrict__ h, const float* __restrict__ Wa,
    const float* __restrict__ Wa_bias, const float* __restrict__ Ua_bias,
    float* __restrict__ hw) {
  int idx = blockIdx.x * blockDim.x + threadIdx.x;  // 16384 = B*U
  int b = idx >> 9;
  int u = idx & 511;
  float acc = Wa_bias[u] + Ua_bias[u];
  const float* hrow = h + b * UU;
  for (int f = 0; f < FF; ++f) acc += hrow[f] * Wa[f * UU + u];
  hw[idx] = acc;
}

// Pack Ua (fp32 [k][n]) into fragment-native bf16 layout:
// Up[((n16*16 + k32)*64 + lane)*8 + i], where n = n16*16 + (lane&15),
// k = k32*32 + (i<4 ? 4*(lane>>4)+i : 16 + 4*(lane>>4) + (i-4)).
__global__ __launch_bounds__(64) void k0_pack(
    const float* __restrict__ Ua, short* __restrict__ Up) {
  const int n16 = blockIdx.x;   // 0..31
  const int k32 = blockIdx.y;   // 0..15
  const int l = threadIdx.x;    // 0..63
  const int n = n16 * 16 + (l & 15);
  const int g = l >> 4;
  bf16x8 v;
#pragma unroll
  for (int i = 0; i < 8; ++i) {
    int k = k32 * 32 + (i < 4 ? g * 4 + i : 16 + g * 4 + (i - 4));
    v[i] = f2bf(Ua[k * UU + n]);
  }
  *reinterpret_cast<bf16x8*>(Up + ((size_t)(n16 * 16 + k32) * 64 + l) * 8) = v;
}

// MFMA scores kernel: block = (t-tile of 64) x (all 512 u), 4 waves.
// scores[b][t] = sum_u tanh(ann[b,t,:]@Ua[:,u] + hw[b,u]) * Va[u]
__global__ __launch_bounds__(256, 2) void k2_mfma(
    const float* __restrict__ ann, const short* __restrict__ Up,
    const float* __restrict__ Va, const float* __restrict__ hw,
    float* __restrict__ scores) {
  __shared__ short As[64][72];     // padded: 2-way bank conflicts only
  __shared__ float red[4][64];
  const int b = blockIdx.z;
  const int t0 = blockIdx.x * 64;
  const int tid = threadIdx.x;
  const int w = tid >> 6;          // wave 0..3 -> u-slice [w*128, w*128+128)
  const int l = tid & 63;
  const int lo = l & 15;
  const int g = l >> 4;

  const float* annb = ann + (size_t)b * TT * FF + (size_t)t0 * FF;

  // A staging: thread loads 16 floats of chunk (row = tid>>2, 64B col slice)
  const int arow = tid >> 2;          // 0..63
  const int acol = (tid & 3) * 16;    // 0,16,32,48

  f32x4 pf[4];
#pragma unroll
  for (int i = 0; i < 4; ++i)
    pf[i] = *reinterpret_cast<const f32x4*>(annb + (size_t)arow * FF + acol + i * 4);

  f32x4 acc[4][8];
#pragma unroll
  for (int mf = 0; mf < 4; ++mf)
#pragma unroll
    for (int nf = 0; nf < 8; ++nf) acc[mf][nf] = (f32x4)0.f;

  for (int kc = 0; kc < 8; ++kc) {
    __syncthreads();   // protect previous-iteration LDS reads
#pragma unroll
    for (int i = 0; i < 4; ++i) {
      bf16x4 t;
      t[0] = f2bf(pf[i].x); t[1] = f2bf(pf[i].y);
      t[2] = f2bf(pf[i].z); t[3] = f2bf(pf[i].w);
      *reinterpret_cast<bf16x4*>(&As[arow][acol + i * 4]) = t;
    }
    __syncthreads();
    if (kc < 7) {
      const float* src = annb + (size_t)arow * FF + (kc + 1) * 64 + acol;
#pragma unroll
      for (int i = 0; i < 4; ++i)
        pf[i] = *reinterpret_cast<const f32x4*>(src + i * 4);
    }
#pragma unroll
    for (int ks = 0; ks < 2; ++ks) {
      const int k32 = kc * 2 + ks;
      bf16x8 bfr[8];
#pragma unroll
      for (int nf = 0; nf < 8; ++nf) {
        const int n16 = w * 8 + nf;
        bfr[nf] = *reinterpret_cast<const bf16x8*>(
            Up + ((size_t)(n16 * 16 + k32) * 64 + l) * 8);
      }
      bf16x8 af[4];
#pragma unroll
      for (int mf = 0; mf < 4; ++mf) {
        const int m = mf * 16 + lo;
        const int kb = ks * 32 + g * 4;
        bf16x4 h0 = *reinterpret_cast<const bf16x4*>(&As[m][kb]);
        bf16x4 h1 = *reinterpret_cast<const bf16x4*>(&As[m][kb + 16]);
        af[mf] = __builtin_shufflevector(h0, h1, 0, 1, 2, 3, 4, 5, 6, 7);
      }
#pragma unroll
      for (int mf = 0; mf < 4; ++mf)
#pragma unroll
        for (int nf = 0; nf < 8; ++nf)
          acc[mf][nf] = __builtin_amdgcn_mfma_f32_16x16x32_bf16(
              af[mf], bfr[nf], acc[mf][nf], 0, 0, 0);
    }
  }

  // epilogue: part[mf][r] = sum_nf tanh(acc + hw[u]) * Va[u]
  const float* hwb = hw + b * UU;
  float part[4][4];
#pragma unroll
  for (int mf = 0; mf < 4; ++mf)
#pragma unroll
    for (int r = 0; r < 4; ++r) part[mf][r] = 0.f;
#pragma unroll
  for (int nf = 0; nf < 8; ++nf) {
    const int u = w * 128 + nf * 16 + lo;
    const float hv = hwb[u];
    const float vv = Va[u];
#pragma unroll
    for (int mf = 0; mf < 4; ++mf)
#pragma unroll
      for (int r = 0; r < 4; ++r)
        part[mf][r] += tanhf(acc[mf][nf][r] + hv) * vv;
  }
  // reduce over the 16 lanes (lo) holding different u of same t-row
#pragma unroll
  for (int mf = 0; mf < 4; ++mf)
#pragma unroll
    for (int r = 0; r < 4; ++r) {
      float s = part[mf][r];
      s += __shfl_xor(s, 1);
      s += __shfl_xor(s, 2);
      s += __shfl_xor(s, 4);
      s += __shfl_xor(s, 8);
      part[mf][r] = s;
    }
  if (lo == 0) {
#pragma unroll
    for (int mf = 0; mf < 4; ++mf)
#pragma unroll
      for (int r = 0; r < 4; ++r)
        red[w][mf * 16 + g * 4 + r] = part[mf][r];
  }
  __syncthreads();
  if (tid < 64)
    scores[b * TT + t0 + tid] =
        red[0][tid] + red[1][tid] + red[2][tid] + red[3][tid];
}

__global__ __launch_bounds__(256) void k3_softmax(
    const float* __restrict__ scores, float* __restrict__ alpha) {
  const int b = blockIdx.x;
  const int tid = threadIdx.x;
  __shared__ float red[256];
  float v[8];
  float m = -1e30f;
#pragma unroll
  for (int i = 0; i < 8; ++i) {
    v[i] = scores[b * TT + tid + i * 256];
    m = fmaxf(m, v[i]);
  }
  red[tid] = m;
  __syncthreads();
  for (int s = 128; s > 0; s >>= 1) {
    if (tid < s) red[tid] = fmaxf(red[tid], red[tid + s]);
    __syncthreads();
  }
  m = red[0];
  __syncthreads();
  float sum = 0.f;
#pragma unroll
  for (int i = 0; i < 8; ++i) {
    v[i] = expf(v[i] - m);
    sum += v[i];
  }
  red[tid] = sum;
  __syncthreads();
  for (int s = 128; s > 0; s >>= 1) {
    if (tid < s) red[tid] += red[tid + s];
    __syncthreads();
  }
  float inv = 1.f / red[0];
#pragma unroll
  for (int i = 0; i < 8; ++i) alpha[b * TT + tid + i * 256] = v[i] * inv;
}

__global__ __launch_bounds__(256) void k4_context(
    const float* __restrict__ ann, const float* __restrict__ alpha,
    float* __restrict__ c) {
  const int b = blockIdx.y;
  const int t0 = blockIdx.x * 64;
  const int tid = threadIdx.x;
  float2 acc = {0.f, 0.f};
  const float* base = ann + (size_t)b * TT * FF;
  for (int tt = 0; tt < 64; ++tt) {
    int t = t0 + tt;
    float a = alpha[b * TT + t];
    const float2 v = *reinterpret_cast<const float2*>(base + (size_t)t * FF + tid * 2);
    acc.x += a * v.x;
    acc.y += a * v.y;
  }
  atomicAdd(&c[b * FF + tid * 2], acc.x);
  atomicAdd(&c[b * FF + tid * 2 + 1], acc.y);
}

// One block per batch row. Note: reference's `r * h @ rk` = (r*h) @ rk.
__global__ __launch_bounds__(512) void k5_cell(
    const float* __restrict__ x, const float* __restrict__ h,
    const float* __restrict__ c, const float* __restrict__ kern,
    const float* __restrict__ rk, const float* __restrict__ ak,
    const float* __restrict__ bias, const float* __restrict__ abias,
    float* __restrict__ out) {
  const int b = blockIdx.x;
  const int u = threadIdx.x;  // 0..511
  __shared__ float xs[512], cs[512], hs[512], rhs[512];
  xs[u] = x[b * FF + u];
  cs[u] = c[b * FF + u];
  hs[u] = h[b * UU + u];
  __syncthreads();

  float xz = bias[u], xr = bias[u + UU], xh = bias[u + 2 * UU];
  float az = abias[u], ar = abias[u + UU], ah = abias[u + 2 * UU];
  float hz = 0.f, hr = 0.f;
  for (int f = 0; f < FF; ++f) {
    float xv = xs[f], cv = cs[f], hv = hs[f];
    const float* kf = kern + (size_t)f * 3 * UU;
    const float* af = ak + (size_t)f * 3 * UU;
    const float* rf = rk + (size_t)f * 3 * UU;
    xz += xv * kf[u]; xr += xv * kf[u + UU]; xh += xv * kf[u + 2 * UU];
    az += cv * af[u]; ar += cv * af[u + UU]; ah += cv * af[u + 2 * UU];
    hz += hv * rf[u]; hr += hv * rf[u + UU];
  }
  float z = fminf(fmaxf(0.2f * (xz + hz + az) + 0.5f, 0.f), 1.f);
  float r = fminf(fmaxf(0.2f * (xr + hr + ar) + 0.5f, 0.f), 1.f);
  rhs[u] = r * hs[u];
  __syncthreads();

  float q = 0.f;
  for (int f = 0; f < FF; ++f) q += rhs[f] * rk[(size_t)f * 3 * UU + 2 * UU + u];
  float hh = tanhf(xh + q + ah);
  out[b * UU + u] = z * hs[u] + (1.f - z) * hh;
}

extern "C" void kernel_launch(void* const* d_in, const int* in_sizes, int n_in,
                              void* d_out, int out_size, void* d_ws, size_t ws_size,
                              hipStream_t stream) {
  const float* x       = (const float*)d_in[0];
  const float* h       = (const float*)d_in[1];
  const float* ann     = (const float*)d_in[2];
  const float* kern    = (const float*)d_in[3];
  const float* rk      = (const float*)d_in[4];
  const float* ak      = (const float*)d_in[5];
  const float* Wa      = (const float*)d_in[6];
  const float* Ua      = (const float*)d_in[7];
  const float* Va      = (const float*)d_in[8];
  const float* bias    = (const float*)d_in[9];
  const float* abias   = (const float*)d_in[10];
  const float* Wa_bias = (const float*)d_in[11];
  const float* Ua_bias = (const float*)d_in[12];

  float* ws     = (float*)d_ws;
  float* hw     = ws;            // 16384
  float* alpha  = ws + 16384;    // 65536
  float* scores = ws + 81920;    // 65536
  float* c      = ws + 147456;   // 16384
  short* Up     = (short*)(ws + 163840);  // 262144 shorts (512KB)

  // zero the atomic-accumulation target c
  hipMemsetAsync(c, 0, 16384 * sizeof(float), stream);

  dim3 g0(32, 16);
  k0_pack<<<g0, 64, 0, stream>>>(Ua, Up);

  k1_hw<<<64, 256, 0, stream>>>(h, Wa, Wa_bias, Ua_bias, hw);

  dim3 g2(TT / 64, 1, BB);
  k2_mfma<<<g2, 256, 0, stream>>>(ann, Up, Va, hw, scores);

  k3_softmax<<<BB, 256, 0, stream>>>(scores, alpha);

  dim3 g4(TT / 64, BB);
  k4_context<<<g4, 256, 0, stream>>>(ann, alpha, c);

  k5_cell<<<BB, 512, 0, stream>>>(x, h, c, kern, rk, ak, bias, abias,
                                  (float*)d_out);
}

// Round 4
// 178.968 us; speedup vs baseline: 4.4395x; 1.3060x over previous
//
#include <hip/hip_runtime.h>
#include <hip/hip_bf16.h>
#include <math.h>

#define BB 32
#define TT 2048
#define FF 512
#define UU 512

typedef __attribute__((ext_vector_type(4))) float f32x4;
typedef __attribute__((ext_vector_type(4))) short bf16x4;
typedef __attribute__((ext_vector_type(8))) short bf16x8;

__device__ inline short f2bf(float f) {
  union { __hip_bfloat16 h; short s; } u;
  u.h = __float2bfloat16(f);
  return u.s;
}

// ws layout (floats):
// hw:     [0,      16384)
// alpha:  [16384,  81920)
// scores: [81920,  147456)
// c:      [147456, 163840)   -- atomic target, zeroed mid-stream
// G:      [163840, 212992)   -- atomic target, zeroed mid-stream (overlays Up)
// qbuf:   [212992, 229376)   -- atomic target, zeroed mid-stream (overlays Up)
// zs:     [229376, 245760)   -- overlays Up
// rh:     [245760, 262144)   -- overlays Up
// Up:     shorts at float-offset 163840..294912 -- dead after k2; memset after
//         k3 destroys it (safe, stream-ordered).

__global__ __launch_bounds__(256) void k1_hw(
    const float* __restrict__ h, const float* __restrict__ Wa,
    const float* __restrict__ Wa_bias, const float* __restrict__ Ua_bias,
    float* __restrict__ hw) {
  int idx = blockIdx.x * blockDim.x + threadIdx.x;  // 16384 = B*U
  int b = idx >> 9;
  int u = idx & 511;
  float acc = Wa_bias[u] + Ua_bias[u];
  const float* hrow = h + b * UU;
  for (int f = 0; f < FF; ++f) acc += hrow[f] * Wa[f * UU + u];
  hw[idx] = acc;
}

// Pack Ua (fp32 [k][n]) into fragment-native bf16 layout.
__global__ __launch_bounds__(64) void k0_pack(
    const float* __restrict__ Ua, short* __restrict__ Up) {
  const int n16 = blockIdx.x;   // 0..31
  const int k32 = blockIdx.y;   // 0..15
  const int l = threadIdx.x;    // 0..63
  const int n = n16 * 16 + (l & 15);
  const int g = l >> 4;
  bf16x8 v;
#pragma unroll
  for (int i = 0; i < 8; ++i) {
    int k = k32 * 32 + (i < 4 ? g * 4 + i : 16 + g * 4 + (i - 4));
    v[i] = f2bf(Ua[k * UU + n]);
  }
  *reinterpret_cast<bf16x8*>(Up + ((size_t)(n16 * 16 + k32) * 64 + l) * 8) = v;
}

// MFMA scores kernel: block = (t-tile of 64) x (all 512 u), 4 waves.
__global__ __launch_bounds__(256, 2) void k2_mfma(
    const float* __restrict__ ann, const short* __restrict__ Up,
    const float* __restrict__ Va, const float* __restrict__ hw,
    float* __restrict__ scores) {
  __shared__ short As[64][72];
  __shared__ float red[4][64];
  const int b = blockIdx.z;
  const int t0 = blockIdx.x * 64;
  const int tid = threadIdx.x;
  const int w = tid >> 6;
  const int l = tid & 63;
  const int lo = l & 15;
  const int g = l >> 4;

  const float* annb = ann + (size_t)b * TT * FF + (size_t)t0 * FF;

  const int arow = tid >> 2;
  const int acol = (tid & 3) * 16;

  f32x4 pf[4];
#pragma unroll
  for (int i = 0; i < 4; ++i)
    pf[i] = *reinterpret_cast<const f32x4*>(annb + (size_t)arow * FF + acol + i * 4);

  f32x4 acc[4][8];
#pragma unroll
  for (int mf = 0; mf < 4; ++mf)
#pragma unroll
    for (int nf = 0; nf < 8; ++nf) acc[mf][nf] = (f32x4)0.f;

  for (int kc = 0; kc < 8; ++kc) {
    __syncthreads();
#pragma unroll
    for (int i = 0; i < 4; ++i) {
      bf16x4 t;
      t[0] = f2bf(pf[i].x); t[1] = f2bf(pf[i].y);
      t[2] = f2bf(pf[i].z); t[3] = f2bf(pf[i].w);
      *reinterpret_cast<bf16x4*>(&As[arow][acol + i * 4]) = t;
    }
    __syncthreads();
    if (kc < 7) {
      const float* src = annb + (size_t)arow * FF + (kc + 1) * 64 + acol;
#pragma unroll
      for (int i = 0; i < 4; ++i)
        pf[i] = *reinterpret_cast<const f32x4*>(src + i * 4);
    }
#pragma unroll
    for (int ks = 0; ks < 2; ++ks) {
      const int k32 = kc * 2 + ks;
      bf16x8 bfr[8];
#pragma unroll
      for (int nf = 0; nf < 8; ++nf) {
        const int n16 = w * 8 + nf;
        bfr[nf] = *reinterpret_cast<const bf16x8*>(
            Up + ((size_t)(n16 * 16 + k32) * 64 + l) * 8);
      }
      bf16x8 af[4];
#pragma unroll
      for (int mf = 0; mf < 4; ++mf) {
        const int m = mf * 16 + lo;
        const int kb = ks * 32 + g * 4;
        bf16x4 h0 = *reinterpret_cast<const bf16x4*>(&As[m][kb]);
        bf16x4 h1 = *reinterpret_cast<const bf16x4*>(&As[m][kb + 16]);
        af[mf] = __builtin_shufflevector(h0, h1, 0, 1, 2, 3, 4, 5, 6, 7);
      }
#pragma unroll
      for (int mf = 0; mf < 4; ++mf)
#pragma unroll
        for (int nf = 0; nf < 8; ++nf)
          acc[mf][nf] = __builtin_amdgcn_mfma_f32_16x16x32_bf16(
              af[mf], bfr[nf], acc[mf][nf], 0, 0, 0);
    }
  }

  const float* hwb = hw + b * UU;
  float part[4][4];
#pragma unroll
  for (int mf = 0; mf < 4; ++mf)
#pragma unroll
    for (int r = 0; r < 4; ++r) part[mf][r] = 0.f;
#pragma unroll
  for (int nf = 0; nf < 8; ++nf) {
    const int u = w * 128 + nf * 16 + lo;
    const float hv = hwb[u];
    const float vv = Va[u];
#pragma unroll
    for (int mf = 0; mf < 4; ++mf)
#pragma unroll
      for (int r = 0; r < 4; ++r)
        part[mf][r] += tanhf(acc[mf][nf][r] + hv) * vv;
  }
#pragma unroll
  for (int mf = 0; mf < 4; ++mf)
#pragma unroll
    for (int r = 0; r < 4; ++r) {
      float s = part[mf][r];
      s += __shfl_xor(s, 1);
      s += __shfl_xor(s, 2);
      s += __shfl_xor(s, 4);
      s += __shfl_xor(s, 8);
      part[mf][r] = s;
    }
  if (lo == 0) {
#pragma unroll
    for (int mf = 0; mf < 4; ++mf)
#pragma unroll
      for (int r = 0; r < 4; ++r)
        red[w][mf * 16 + g * 4 + r] = part[mf][r];
  }
  __syncthreads();
  if (tid < 64)
    scores[b * TT + t0 + tid] =
        red[0][tid] + red[1][tid] + red[2][tid] + red[3][tid];
}

__global__ __launch_bounds__(256) void k3_softmax(
    const float* __restrict__ scores, float* __restrict__ alpha) {
  const int b = blockIdx.x;
  const int tid = threadIdx.x;
  __shared__ float red[256];
  float v[8];
  float m = -1e30f;
#pragma unroll
  for (int i = 0; i < 8; ++i) {
    v[i] = scores[b * TT + tid + i * 256];
    m = fmaxf(m, v[i]);
  }
  red[tid] = m;
  __syncthreads();
  for (int s = 128; s > 0; s >>= 1) {
    if (tid < s) red[tid] = fmaxf(red[tid], red[tid + s]);
    __syncthreads();
  }
  m = red[0];
  __syncthreads();
  float sum = 0.f;
#pragma unroll
  for (int i = 0; i < 8; ++i) {
    v[i] = expf(v[i] - m);
    sum += v[i];
  }
  red[tid] = sum;
  __syncthreads();
  for (int s = 128; s > 0; s >>= 1) {
    if (tid < s) red[tid] += red[tid + s];
    __syncthreads();
  }
  float inv = 1.f / red[0];
#pragma unroll
  for (int i = 0; i < 8; ++i) alpha[b * TT + tid + i * 256] = v[i] * inv;
}

__global__ __launch_bounds__(256) void k4_context(
    const float* __restrict__ ann, const float* __restrict__ alpha,
    float* __restrict__ c) {
  const int b = blockIdx.y;
  const int t0 = blockIdx.x * 64;
  const int tid = threadIdx.x;
  float2 acc = {0.f, 0.f};
  const float* base = ann + (size_t)b * TT * FF;
  for (int tt = 0; tt < 64; ++tt) {
    int t = t0 + tt;
    float a = alpha[b * TT + t];
    const float2 v = *reinterpret_cast<const float2*>(base + (size_t)t * FF + tid * 2);
    acc.x += a * v.x;
    acc.y += a * v.y;
  }
  atomicAdd(&c[b * FF + tid * 2], acc.x);
  atomicAdd(&c[b * FF + tid * 2 + 1], acc.y);
}

// --- gate GEMMs, LDS-tiled ------------------------------------------------
// k5a: G[b][n] = sum_k x[b][k]*kern[k][n] + c[b][k]*ak[k][n]
//               (+ h[b][k]*rk[k][n] for n<1024).  grid (24, 2), atomicAdd.
__global__ __launch_bounds__(512) void k5a_gates(
    const float* __restrict__ x, const float* __restrict__ cc,
    const float* __restrict__ h, const float* __restrict__ kern,
    const float* __restrict__ ak, const float* __restrict__ rk,
    float* __restrict__ G) {
  __shared__ float wsx[64][64], wsa[64][64], wsr[64][64];
  __shared__ float xs[32][64], cs[32][64], hs[32][64];
  const int n0 = blockIdx.x * 64;
  const int kbase = blockIdx.y * 256;
  const bool has_r = (n0 < 1024);
  const int tid = threadIdx.x;
  const int n = tid & 63;
  const int b0 = (tid >> 6) * 4;
  const int wrow = tid >> 3, wcol = (tid & 7) * 8;
  const int orow = tid >> 4, ocol = (tid & 15) * 4;
  float acc[4] = {0.f, 0.f, 0.f, 0.f};

  for (int kt = 0; kt < 4; ++kt) {
    const int kg0 = kbase + kt * 64;
    __syncthreads();
    {
      const size_t wb = (size_t)(kg0 + wrow) * 1536 + n0 + wcol;
      *reinterpret_cast<float4*>(&wsx[wrow][wcol])     = *reinterpret_cast<const float4*>(kern + wb);
      *reinterpret_cast<float4*>(&wsx[wrow][wcol + 4]) = *reinterpret_cast<const float4*>(kern + wb + 4);
      *reinterpret_cast<float4*>(&wsa[wrow][wcol])     = *reinterpret_cast<const float4*>(ak + wb);
      *reinterpret_cast<float4*>(&wsa[wrow][wcol + 4]) = *reinterpret_cast<const float4*>(ak + wb + 4);
      if (has_r) {
        *reinterpret_cast<float4*>(&wsr[wrow][wcol])     = *reinterpret_cast<const float4*>(rk + wb);
        *reinterpret_cast<float4*>(&wsr[wrow][wcol + 4]) = *reinterpret_cast<const float4*>(rk + wb + 4);
      }
      *reinterpret_cast<float4*>(&xs[orow][ocol]) =
          *reinterpret_cast<const float4*>(x + orow * FF + kg0 + ocol);
      *reinterpret_cast<float4*>(&cs[orow][ocol]) =
          *reinterpret_cast<const float4*>(cc + orow * FF + kg0 + ocol);
      *reinterpret_cast<float4*>(&hs[orow][ocol]) =
          *reinterpret_cast<const float4*>(h + orow * UU + kg0 + ocol);
    }
    __syncthreads();
    if (has_r) {
#pragma unroll 8
      for (int k = 0; k < 64; ++k) {
        const float wx = wsx[k][n], wa = wsa[k][n], wr = wsr[k][n];
#pragma unroll
        for (int j = 0; j < 4; ++j)
          acc[j] += xs[b0 + j][k] * wx + cs[b0 + j][k] * wa + hs[b0 + j][k] * wr;
      }
    } else {
#pragma unroll 8
      for (int k = 0; k < 64; ++k) {
        const float wx = wsx[k][n], wa = wsa[k][n];
#pragma unroll
        for (int j = 0; j < 4; ++j)
          acc[j] += xs[b0 + j][k] * wx + cs[b0 + j][k] * wa;
      }
    }
  }
#pragma unroll
  for (int j = 0; j < 4; ++j)
    atomicAdd(&G[(size_t)(b0 + j) * 1536 + n0 + n], acc[j]);
}

// k5b: z, r pointwise; rh = r*h, zs = z.
__global__ __launch_bounds__(256) void k5b_zr(
    const float* __restrict__ G, const float* __restrict__ h,
    const float* __restrict__ bias, const float* __restrict__ abias,
    float* __restrict__ zs, float* __restrict__ rh) {
  int idx = blockIdx.x * blockDim.x + threadIdx.x;  // 16384
  int b = idx >> 9;
  int u = idx & 511;
  float z = 0.2f * (G[(size_t)b * 1536 + u] + bias[u] + abias[u]) + 0.5f;
  z = fminf(fmaxf(z, 0.f), 1.f);
  float r = 0.2f * (G[(size_t)b * 1536 + 512 + u] + bias[512 + u] + abias[512 + u]) + 0.5f;
  r = fminf(fmaxf(r, 0.f), 1.f);
  zs[idx] = z;
  rh[idx] = r * h[idx];
}

// k5c: qbuf[b][u] = sum_k rh[b][k] * rk[k][1024+u].  grid (8, 2), atomicAdd.
__global__ __launch_bounds__(512) void k5c_q(
    const float* __restrict__ rh, const float* __restrict__ rk,
    float* __restrict__ qbuf) {
  __shared__ float wsr[64][64];
  __shared__ float rs[32][64];
  const int n0 = blockIdx.x * 64;
  const int kbase = blockIdx.y * 256;
  const int tid = threadIdx.x;
  const int n = tid & 63;
  const int b0 = (tid >> 6) * 4;
  const int wrow = tid >> 3, wcol = (tid & 7) * 8;
  const int orow = tid >> 4, ocol = (tid & 15) * 4;
  float acc[4] = {0.f, 0.f, 0.f, 0.f};

  for (int kt = 0; kt < 4; ++kt) {
    const int kg0 = kbase + kt * 64;
    __syncthreads();
    const size_t wb = (size_t)(kg0 + wrow) * 1536 + 1024 + n0 + wcol;
    *reinterpret_cast<float4*>(&wsr[wrow][wcol])     = *reinterpret_cast<const float4*>(rk + wb);
    *reinterpret_cast<float4*>(&wsr[wrow][wcol + 4]) = *reinterpret_cast<const float4*>(rk + wb + 4);
    *reinterpret_cast<float4*>(&rs[orow][ocol]) =
        *reinterpret_cast<const float4*>(rh + orow * UU + kg0 + ocol);
    __syncthreads();
#pragma unroll 8
    for (int k = 0; k < 64; ++k) {
      const float w = wsr[k][n];
#pragma unroll
      for (int j = 0; j < 4; ++j) acc[j] += rs[b0 + j][k] * w;
    }
  }
#pragma unroll
  for (int j = 0; j < 4; ++j)
    atomicAdd(&qbuf[(b0 + j) * UU + n0 + n], acc[j]);
}

// k5d: hh = tanh(G_h + biases + q); out = zs*h + (1-zs)*hh.
__global__ __launch_bounds__(256) void k5d_out(
    const float* __restrict__ G, const float* __restrict__ qbuf,
    const float* __restrict__ zs, const float* __restrict__ h,
    const float* __restrict__ bias, const float* __restrict__ abias,
    float* __restrict__ out) {
  int idx = blockIdx.x * blockDim.x + threadIdx.x;  // 16384
  int b = idx >> 9;
  int u = idx & 511;
  float hh = tanhf(G[(size_t)b * 1536 + 1024 + u] + bias[1024 + u] +
                   abias[1024 + u] + qbuf[idx]);
  float z = zs[idx];
  out[idx] = z * h[idx] + (1.f - z) * hh;
}

extern "C" void kernel_launch(void* const* d_in, const int* in_sizes, int n_in,
                              void* d_out, int out_size, void* d_ws, size_t ws_size,
                              hipStream_t stream) {
  const float* x       = (const float*)d_in[0];
  const float* h       = (const float*)d_in[1];
  const float* ann     = (const float*)d_in[2];
  const float* kern    = (const float*)d_in[3];
  const float* rk      = (const float*)d_in[4];
  const float* ak      = (const float*)d_in[5];
  const float* Wa      = (const float*)d_in[6];
  const float* Ua      = (const float*)d_in[7];
  const float* Va      = (const float*)d_in[8];
  const float* bias    = (const float*)d_in[9];
  const float* abias   = (const float*)d_in[10];
  const float* Wa_bias = (const float*)d_in[11];
  const float* Ua_bias = (const float*)d_in[12];

  float* ws     = (float*)d_ws;
  float* hw     = ws;            // 16384
  float* alpha  = ws + 16384;    // 65536
  float* scores = ws + 81920;    // 65536
  float* c      = ws + 147456;   // 16384
  float* G      = ws + 163840;   // 49152 (overlays Up)
  float* qbuf   = ws + 212992;   // 16384 (overlays Up)
  float* zs     = ws + 229376;   // 16384 (overlays Up)
  float* rh     = ws + 245760;   // 16384 (overlays Up)
  short* Up     = (short*)(ws + 163840);  // 262144 shorts; dead after k2

  dim3 g0(32, 16);
  k0_pack<<<g0, 64, 0, stream>>>(Ua, Up);

  k1_hw<<<64, 256, 0, stream>>>(h, Wa, Wa_bias, Ua_bias, hw);

  dim3 g2(TT / 64, 1, BB);
  k2_mfma<<<g2, 256, 0, stream>>>(ann, Up, Va, hw, scores);

  k3_softmax<<<BB, 256, 0, stream>>>(scores, alpha);

  // zero c + G + qbuf (contiguous 81920 floats); destroys Up (dead after k2)
  hipMemsetAsync(c, 0, 81920 * sizeof(float), stream);

  dim3 g4(TT / 64, BB);
  k4_context<<<g4, 256, 0, stream>>>(ann, alpha, c);

  dim3 g5a(24, 2);
  k5a_gates<<<g5a, 512, 0, stream>>>(x, c, h, kern, ak, rk, G);

  k5b_zr<<<64, 256, 0, stream>>>(G, h, bias, abias, zs, rh);

  dim3 g5c(8, 2);
  k5c_q<<<g5c, 512, 0, stream>>>(rh, rk, qbuf);

  k5d_out<<<64, 256, 0, stream>>>(G, qbuf, zs, h, bias, abias, (float*)d_out);
}

// Round 5
// 172.304 us; speedup vs baseline: 4.6113x; 1.0387x over previous
//
#include <hip/hip_runtime.h>
#include <hip/hip_bf16.h>
#include <math.h>

#define BB 32
#define TT 2048
#define FF 512
#define UU 512

typedef __attribute__((ext_vector_type(4))) float f32x4;
typedef __attribute__((ext_vector_type(4))) short bf16x4;
typedef __attribute__((ext_vector_type(8))) short bf16x8;

__device__ inline short f2bf(float f) {
  union { __hip_bfloat16 h; short s; } u;
  u.h = __float2bfloat16(f);
  return u.s;
}

// ws layout (floats):
// hw:     [0,      16384)
// mbuf:   [16384,  17408)    32 b x 32 tiles
// lbuf:   [17408,  18432)
// cpart:  [18432,  542720)   32 b x 32 tiles x 512 f
// c:      [542720, 559104)   direct write by k6
// G:      [559104, 608256)   atomic target, zeroed up front
// qbuf:   [608256, 624640)   atomic target, zeroed up front
// zs:     [624640, 641024)
// rh:     [641024, 657408)
// Up:     shorts at float-offset 657408 (262144 shorts = 512 KB)

__global__ __launch_bounds__(256) void k1_hw(
    const float* __restrict__ h, const float* __restrict__ Wa,
    const float* __restrict__ Wa_bias, const float* __restrict__ Ua_bias,
    float* __restrict__ hw) {
  int idx = blockIdx.x * blockDim.x + threadIdx.x;  // 16384 = B*U
  int b = idx >> 9;
  int u = idx & 511;
  float acc = Wa_bias[u] + Ua_bias[u];
  const float* hrow = h + b * UU;
  for (int f = 0; f < FF; ++f) acc += hrow[f] * Wa[f * UU + u];
  hw[idx] = acc;
}

// Pack Ua (fp32 [k][n]) into fragment-native bf16 layout.
__global__ __launch_bounds__(64) void k0_pack(
    const float* __restrict__ Ua, short* __restrict__ Up) {
  const int n16 = blockIdx.x;   // 0..31
  const int k32 = blockIdx.y;   // 0..15
  const int l = threadIdx.x;    // 0..63
  const int n = n16 * 16 + (l & 15);
  const int g = l >> 4;
  bf16x8 v;
#pragma unroll
  for (int i = 0; i < 8; ++i) {
    int k = k32 * 32 + (i < 4 ? g * 4 + i : 16 + g * 4 + (i - 4));
    v[i] = f2bf(Ua[k * UU + n]);
  }
  *reinterpret_cast<bf16x8*>(Up + ((size_t)(n16 * 16 + k32) * 64 + l) * 8) = v;
}

// Flash kernel: block = (t-tile of 64) x b. Stages the whole 64x512 ann tile
// in LDS in fragment-native layout, computes scores via MFMA, then the
// softmax-partial context from the same LDS tile. ann is read from HBM once.
__global__ __launch_bounds__(256, 2) void k2_flash(
    const float* __restrict__ ann, const short* __restrict__ Up,
    const float* __restrict__ Va, const float* __restrict__ hw,
    float* __restrict__ mbuf, float* __restrict__ lbuf,
    float* __restrict__ cpart) {
  __shared__ short Af[32768];      // 64 fb x 64 lane x 8 bf16 = 64 KB
  __shared__ float red[4][64];
  __shared__ float e_all[64];
  const int tile = blockIdx.x;
  const int b = blockIdx.y;
  const int t0 = tile * 64;
  const int tid = threadIdx.x;
  const int w = tid >> 6;          // wave 0..3
  const int l = tid & 63;
  const int lo = l & 15;
  const int g = l >> 4;

  const float* annb = ann + ((size_t)b * TT + t0) * FF;

  // ---- stage: wave w writes A-fragments for mf=w (rows w*16..w*16+15) ----
#pragma unroll
  for (int v = 0; v < 16; ++v) {   // v = k32
    const float* src = annb + (size_t)(w * 16 + lo) * FF + v * 32 + g * 4;
    f32x4 a0 = *reinterpret_cast<const f32x4*>(src);
    f32x4 a1 = *reinterpret_cast<const f32x4*>(src + 16);
    bf16x8 o;
    o[0] = f2bf(a0.x); o[1] = f2bf(a0.y); o[2] = f2bf(a0.z); o[3] = f2bf(a0.w);
    o[4] = f2bf(a1.x); o[5] = f2bf(a1.y); o[6] = f2bf(a1.z); o[7] = f2bf(a1.w);
    *reinterpret_cast<bf16x8*>(&Af[((w * 16 + v) * 64 + l) * 8]) = o;
  }
  __syncthreads();

  // ---- MFMA: wave w computes all 64 t x u-slice [w*128, w*128+128) ----
  f32x4 acc[4][8];
#pragma unroll
  for (int mf = 0; mf < 4; ++mf)
#pragma unroll
    for (int nf = 0; nf < 8; ++nf) acc[mf][nf] = (f32x4)0.f;

  for (int k32 = 0; k32 < 16; ++k32) {
    bf16x8 af[4];
#pragma unroll
    for (int mf = 0; mf < 4; ++mf)
      af[mf] = *reinterpret_cast<const bf16x8*>(
          &Af[((mf * 16 + k32) * 64 + l) * 8]);
    bf16x8 bfr[8];
#pragma unroll
    for (int nf = 0; nf < 8; ++nf)
      bfr[nf] = *reinterpret_cast<const bf16x8*>(
          Up + ((size_t)((w * 8 + nf) * 16 + k32) * 64 + l) * 8);
#pragma unroll
    for (int mf = 0; mf < 4; ++mf)
#pragma unroll
      for (int nf = 0; nf < 8; ++nf)
        acc[mf][nf] = __builtin_amdgcn_mfma_f32_16x16x32_bf16(
            af[mf], bfr[nf], acc[mf][nf], 0, 0, 0);
  }

  // ---- scores epilogue: tanh(acc + hw[u]) * Va[u], reduce over u ----
  const float* hwb = hw + b * UU;
  float part[4][4];
#pragma unroll
  for (int mf = 0; mf < 4; ++mf)
#pragma unroll
    for (int r = 0; r < 4; ++r) part[mf][r] = 0.f;
#pragma unroll
  for (int nf = 0; nf < 8; ++nf) {
    const int u = w * 128 + nf * 16 + lo;
    const float hv = hwb[u];
    const float vv = Va[u];
#pragma unroll
    for (int mf = 0; mf < 4; ++mf)
#pragma unroll
      for (int r = 0; r < 4; ++r)
        part[mf][r] += tanhf(acc[mf][nf][r] + hv) * vv;
  }
#pragma unroll
  for (int mf = 0; mf < 4; ++mf)
#pragma unroll
    for (int r = 0; r < 4; ++r) {
      float s = part[mf][r];
      s += __shfl_xor(s, 1);
      s += __shfl_xor(s, 2);
      s += __shfl_xor(s, 4);
      s += __shfl_xor(s, 8);
      part[mf][r] = s;
    }
  if (lo == 0) {
#pragma unroll
    for (int mf = 0; mf < 4; ++mf)
#pragma unroll
      for (int r = 0; r < 4; ++r)
        red[w][mf * 16 + g * 4 + r] = part[mf][r];
  }
  __syncthreads();

  // ---- tile softmax stats (wave 0): m, e_t, l ----
  if (tid < 64) {
    float s = red[0][tid] + red[1][tid] + red[2][tid] + red[3][tid];
    float m = s;
#pragma unroll
    for (int off = 1; off < 64; off <<= 1) m = fmaxf(m, __shfl_xor(m, off));
    float e = __expf(s - m);
    float ls = e;
#pragma unroll
    for (int off = 1; off < 64; off <<= 1) ls += __shfl_xor(ls, off);
    e_all[tid] = e;
    if (tid == 0) {
      mbuf[b * 32 + tile] = m;
      lbuf[b * 32 + tile] = ls;
    }
  }
  __syncthreads();

  // ---- partial context: thread owns f = 2*tid, f+1; lane-staggered t ----
  const int f = tid * 2;
  const int kk = f >> 5;
  const int hf = (f >> 4) & 1;
  const int q  = (f >> 2) & 3;
  const int ib = (f & 3) + 4 * hf;   // even -> 4B aligned
  float a0 = 0.f, a1 = 0.f;
  for (int it = 0; it < 64; ++it) {
    const int t = (it + tid) & 63;
    const int idx = (((t >> 4) * 16 + kk) * 64 + q * 16 + (t & 15)) * 8 + ib;
    unsigned vv = *reinterpret_cast<const unsigned*>(&Af[idx]);
    const float e = e_all[t];
    a0 += e * __uint_as_float(vv << 16);
    a1 += e * __uint_as_float(vv & 0xffff0000u);
  }
  float2 st; st.x = a0; st.y = a1;
  *reinterpret_cast<float2*>(&cpart[(size_t)(b * 32 + tile) * 512 + f]) = st;
}

// Combine tile partials: c[b][f] = sum_i w_i*cpart_i[f] / sum_i w_i*l_i,
// w_i = exp(m_i - M).
__global__ __launch_bounds__(256) void k6_combine(
    const float* __restrict__ mbuf, const float* __restrict__ lbuf,
    const float* __restrict__ cpart, float* __restrict__ c) {
  const int b = blockIdx.x;
  const int tid = threadIdx.x;
  __shared__ float sm[32], sl[32];
  if (tid < 32) {
    sm[tid] = mbuf[b * 32 + tid];
    sl[tid] = lbuf[b * 32 + tid];
  }
  __syncthreads();
  float M = -1e30f;
#pragma unroll
  for (int i = 0; i < 32; ++i) M = fmaxf(M, sm[i]);
  float D = 0.f;
#pragma unroll
  for (int i = 0; i < 32; ++i) D += __expf(sm[i] - M) * sl[i];
  const float inv = 1.f / D;
  const int f = tid * 2;
  float a0 = 0.f, a1 = 0.f;
  for (int i = 0; i < 32; ++i) {
    const float wi = __expf(sm[i] - M);
    const float2 v = *reinterpret_cast<const float2*>(
        &cpart[(size_t)(b * 32 + i) * 512 + f]);
    a0 += wi * v.x;
    a1 += wi * v.y;
  }
  c[b * FF + f]     = a0 * inv;
  c[b * FF + f + 1] = a1 * inv;
}

// --- gate GEMMs, LDS-tiled ------------------------------------------------
__global__ __launch_bounds__(512) void k5a_gates(
    const float* __restrict__ x, const float* __restrict__ cc,
    const float* __restrict__ h, const float* __restrict__ kern,
    const float* __restrict__ ak, const float* __restrict__ rk,
    float* __restrict__ G) {
  __shared__ float wsx[64][64], wsa[64][64], wsr[64][64];
  __shared__ float xs[32][64], cs[32][64], hs[32][64];
  const int n0 = blockIdx.x * 64;
  const int kbase = blockIdx.y * 256;
  const bool has_r = (n0 < 1024);
  const int tid = threadIdx.x;
  const int n = tid & 63;
  const int b0 = (tid >> 6) * 4;
  const int wrow = tid >> 3, wcol = (tid & 7) * 8;
  const int orow = tid >> 4, ocol = (tid & 15) * 4;
  float acc[4] = {0.f, 0.f, 0.f, 0.f};

  for (int kt = 0; kt < 4; ++kt) {
    const int kg0 = kbase + kt * 64;
    __syncthreads();
    {
      const size_t wb = (size_t)(kg0 + wrow) * 1536 + n0 + wcol;
      *reinterpret_cast<float4*>(&wsx[wrow][wcol])     = *reinterpret_cast<const float4*>(kern + wb);
      *reinterpret_cast<float4*>(&wsx[wrow][wcol + 4]) = *reinterpret_cast<const float4*>(kern + wb + 4);
      *reinterpret_cast<float4*>(&wsa[wrow][wcol])     = *reinterpret_cast<const float4*>(ak + wb);
      *reinterpret_cast<float4*>(&wsa[wrow][wcol + 4]) = *reinterpret_cast<const float4*>(ak + wb + 4);
      if (has_r) {
        *reinterpret_cast<float4*>(&wsr[wrow][wcol])     = *reinterpret_cast<const float4*>(rk + wb);
        *reinterpret_cast<float4*>(&wsr[wrow][wcol + 4]) = *reinterpret_cast<const float4*>(rk + wb + 4);
      }
      *reinterpret_cast<float4*>(&xs[orow][ocol]) =
          *reinterpret_cast<const float4*>(x + orow * FF + kg0 + ocol);
      *reinterpret_cast<float4*>(&cs[orow][ocol]) =
          *reinterpret_cast<const float4*>(cc + orow * FF + kg0 + ocol);
      *reinterpret_cast<float4*>(&hs[orow][ocol]) =
          *reinterpret_cast<const float4*>(h + orow * UU + kg0 + ocol);
    }
    __syncthreads();
    if (has_r) {
#pragma unroll 8
      for (int k = 0; k < 64; ++k) {
        const float wx = wsx[k][n], wa = wsa[k][n], wr = wsr[k][n];
#pragma unroll
        for (int j = 0; j < 4; ++j)
          acc[j] += xs[b0 + j][k] * wx + cs[b0 + j][k] * wa + hs[b0 + j][k] * wr;
      }
    } else {
#pragma unroll 8
      for (int k = 0; k < 64; ++k) {
        const float wx = wsx[k][n], wa = wsa[k][n];
#pragma unroll
        for (int j = 0; j < 4; ++j)
          acc[j] += xs[b0 + j][k] * wx + cs[b0 + j][k] * wa;
      }
    }
  }
#pragma unroll
  for (int j = 0; j < 4; ++j)
    atomicAdd(&G[(size_t)(b0 + j) * 1536 + n0 + n], acc[j]);
}

__global__ __launch_bounds__(256) void k5b_zr(
    const float* __restrict__ G, const float* __restrict__ h,
    const float* __restrict__ bias, const float* __restrict__ abias,
    float* __restrict__ zs, float* __restrict__ rh) {
  int idx = blockIdx.x * blockDim.x + threadIdx.x;  // 16384
  int b = idx >> 9;
  int u = idx & 511;
  float z = 0.2f * (G[(size_t)b * 1536 + u] + bias[u] + abias[u]) + 0.5f;
  z = fminf(fmaxf(z, 0.f), 1.f);
  float r = 0.2f * (G[(size_t)b * 1536 + 512 + u] + bias[512 + u] + abias[512 + u]) + 0.5f;
  r = fminf(fmaxf(r, 0.f), 1.f);
  zs[idx] = z;
  rh[idx] = r * h[idx];
}

__global__ __launch_bounds__(512) void k5c_q(
    const float* __restrict__ rh, const float* __restrict__ rk,
    float* __restrict__ qbuf) {
  __shared__ float wsr[64][64];
  __shared__ float rs[32][64];
  const int n0 = blockIdx.x * 64;
  const int kbase = blockIdx.y * 256;
  const int tid = threadIdx.x;
  const int n = tid & 63;
  const int b0 = (tid >> 6) * 4;
  const int wrow = tid >> 3, wcol = (tid & 7) * 8;
  const int orow = tid >> 4, ocol = (tid & 15) * 4;
  float acc[4] = {0.f, 0.f, 0.f, 0.f};

  for (int kt = 0; kt < 4; ++kt) {
    const int kg0 = kbase + kt * 64;
    __syncthreads();
    const size_t wb = (size_t)(kg0 + wrow) * 1536 + 1024 + n0 + wcol;
    *reinterpret_cast<float4*>(&wsr[wrow][wcol])     = *reinterpret_cast<const float4*>(rk + wb);
    *reinterpret_cast<float4*>(&wsr[wrow][wcol + 4]) = *reinterpret_cast<const float4*>(rk + wb + 4);
    *reinterpret_cast<float4*>(&rs[orow][ocol]) =
        *reinterpret_cast<const float4*>(rh + orow * UU + kg0 + ocol);
    __syncthreads();
#pragma unroll 8
    for (int k = 0; k < 64; ++k) {
      const float w = wsr[k][n];
#pragma unroll
      for (int j = 0; j < 4; ++j) acc[j] += rs[b0 + j][k] * w;
    }
  }
#pragma unroll
  for (int j = 0; j < 4; ++j)
    atomicAdd(&qbuf[(b0 + j) * UU + n0 + n], acc[j]);
}

__global__ __launch_bounds__(256) void k5d_out(
    const float* __restrict__ G, const float* __restrict__ qbuf,
    const float* __restrict__ zs, const float* __restrict__ h,
    const float* __restrict__ bias, const float* __restrict__ abias,
    float* __restrict__ out) {
  int idx = blockIdx.x * blockDim.x + threadIdx.x;  // 16384
  int b = idx >> 9;
  int u = idx & 511;
  float hh = tanhf(G[(size_t)b * 1536 + 1024 + u] + bias[1024 + u] +
                   abias[1024 + u] + qbuf[idx]);
  float z = zs[idx];
  out[idx] = z * h[idx] + (1.f - z) * hh;
}

extern "C" void kernel_launch(void* const* d_in, const int* in_sizes, int n_in,
                              void* d_out, int out_size, void* d_ws, size_t ws_size,
                              hipStream_t stream) {
  const float* x       = (const float*)d_in[0];
  const float* h       = (const float*)d_in[1];
  const float* ann     = (const float*)d_in[2];
  const float* kern    = (const float*)d_in[3];
  const float* rk      = (const float*)d_in[4];
  const float* ak      = (const float*)d_in[5];
  const float* Wa      = (const float*)d_in[6];
  const float* Ua      = (const float*)d_in[7];
  const float* Va      = (const float*)d_in[8];
  const float* bias    = (const float*)d_in[9];
  const float* abias   = (const float*)d_in[10];
  const float* Wa_bias = (const float*)d_in[11];
  const float* Ua_bias = (const float*)d_in[12];

  float* ws     = (float*)d_ws;
  float* hw     = ws;            // 16384
  float* mbuf   = ws + 16384;    // 1024
  float* lbuf   = ws + 17408;    // 1024
  float* cpart  = ws + 18432;    // 524288
  float* c      = ws + 542720;   // 16384
  float* G      = ws + 559104;   // 49152
  float* qbuf   = ws + 608256;   // 16384
  float* zs     = ws + 624640;   // 16384
  float* rh     = ws + 641024;   // 16384
  short* Up     = (short*)(ws + 657408);  // 262144 shorts

  // zero atomic targets G + qbuf (contiguous 65536 floats)
  hipMemsetAsync(G, 0, 65536 * sizeof(float), stream);

  dim3 g0(32, 16);
  k0_pack<<<g0, 64, 0, stream>>>(Ua, Up);

  k1_hw<<<64, 256, 0, stream>>>(h, Wa, Wa_bias, Ua_bias, hw);

  dim3 g2(TT / 64, BB);
  k2_flash<<<g2, 256, 0, stream>>>(ann, Up, Va, hw, mbuf, lbuf, cpart);

  k6_combine<<<BB, 256, 0, stream>>>(mbuf, lbuf, cpart, c);

  dim3 g5a(24, 2);
  k5a_gates<<<g5a, 512, 0, stream>>>(x, c, h, kern, ak, rk, G);

  k5b_zr<<<64, 256, 0, stream>>>(G, h, bias, abias, zs, rh);

  dim3 g5c(8, 2);
  k5c_q<<<g5c, 512, 0, stream>>>(rh, rk, qbuf);

  k5d_out<<<64, 256, 0, stream>>>(G, qbuf, zs, h, bias, abias, (float*)d_out);
}

// Round 6
// 109.283 us; speedup vs baseline: 7.2705x; 1.5767x over previous
//
#include <hip/hip_runtime.h>
#include <hip/hip_bf16.h>
#include <math.h>

#define BB 32
#define TT 2048
#define FF 512
#define UU 512

typedef __attribute__((ext_vector_type(4))) float f32x4;
typedef __attribute__((ext_vector_type(4))) short bf16x4;
typedef __attribute__((ext_vector_type(8))) short bf16x8;

__device__ inline short f2bf(float f) {
  union { __hip_bfloat16 h; short s; } u;
  u.h = __float2bfloat16(f);
  return u.s;
}

// tanh(x) = 1 - 2/(exp(2x)+1). v_exp + v_rcp: ~6 VALU ops, ~1e-6 abs err.
// Saturates correctly: x>>0 -> e=inf -> 1; x<<0 -> e=0 -> -1.
__device__ inline float tanh_fast(float x) {
  float e = __expf(2.0f * x);
  return 1.0f - 2.0f * __builtin_amdgcn_rcpf(e + 1.0f);
}

// ws layout (floats):
// hw:     [0,      16384)
// mbuf:   [16384,  17408)    32 b x 32 tiles
// lbuf:   [17408,  18432)
// cpart:  [18432,  542720)   32 b x 32 tiles x 512 f
// c:      [542720, 559104)   direct write by k6
// G:      [559104, 608256)   atomic target, zeroed up front
// qbuf:   [608256, 624640)   atomic target, zeroed up front
// zs:     [624640, 641024)
// rh:     [641024, 657408)
// Up:     shorts at float-offset 657408 (262144 shorts = 512 KB)

__global__ __launch_bounds__(256) void k1_hw(
    const float* __restrict__ h, const float* __restrict__ Wa,
    const float* __restrict__ Wa_bias, const float* __restrict__ Ua_bias,
    float* __restrict__ hw) {
  int idx = blockIdx.x * blockDim.x + threadIdx.x;  // 16384 = B*U
  int b = idx >> 9;
  int u = idx & 511;
  float acc = Wa_bias[u] + Ua_bias[u];
  const float* hrow = h + b * UU;
  for (int f = 0; f < FF; ++f) acc += hrow[f] * Wa[f * UU + u];
  hw[idx] = acc;
}

// Pack Ua (fp32 [k][n]) into fragment-native bf16 layout.
__global__ __launch_bounds__(64) void k0_pack(
    const float* __restrict__ Ua, short* __restrict__ Up) {
  const int n16 = blockIdx.x;   // 0..31
  const int k32 = blockIdx.y;   // 0..15
  const int l = threadIdx.x;    // 0..63
  const int n = n16 * 16 + (l & 15);
  const int g = l >> 4;
  bf16x8 v;
#pragma unroll
  for (int i = 0; i < 8; ++i) {
    int k = k32 * 32 + (i < 4 ? g * 4 + i : 16 + g * 4 + (i - 4));
    v[i] = f2bf(Ua[k * UU + n]);
  }
  *reinterpret_cast<bf16x8*>(Up + ((size_t)(n16 * 16 + k32) * 64 + l) * 8) = v;
}

// Flash kernel v2: block = (t-tile of 64) x b, 512 threads (8 waves).
// Wave w owns u-slice [64w, 64w+64): mf=0..3, nf=0..3. acc = 64 VGPR.
__global__ __launch_bounds__(512, 4) void k2_flash(
    const float* __restrict__ ann, const short* __restrict__ Up,
    const float* __restrict__ Va, const float* __restrict__ hw,
    float* __restrict__ mbuf, float* __restrict__ lbuf,
    float* __restrict__ cpart) {
  __shared__ short Af[32768];      // 64 fb x 64 lane x 8 bf16 = 64 KB
  __shared__ float red[8][64];
  __shared__ float e_all[64];
  const int tile = blockIdx.x;
  const int b = blockIdx.y;
  const int t0 = tile * 64;
  const int tid = threadIdx.x;
  const int w = tid >> 6;          // wave 0..7
  const int l = tid & 63;
  const int lo = l & 15;
  const int g = l >> 4;

  const float* annb = ann + ((size_t)b * TT + t0) * FF;

  // ---- stage: wave w writes fb entries mf_s = w>>1, k32 = (w&1)*8 + v ----
  {
    const int mf_s = w >> 1;
    const int kb_s = (w & 1) * 8;
#pragma unroll
    for (int v = 0; v < 8; ++v) {
      const int k32 = kb_s + v;
      const float* src = annb + (size_t)(mf_s * 16 + lo) * FF + k32 * 32 + g * 4;
      f32x4 a0 = *reinterpret_cast<const f32x4*>(src);
      f32x4 a1 = *reinterpret_cast<const f32x4*>(src + 16);
      bf16x8 o;
      o[0] = f2bf(a0.x); o[1] = f2bf(a0.y); o[2] = f2bf(a0.z); o[3] = f2bf(a0.w);
      o[4] = f2bf(a1.x); o[5] = f2bf(a1.y); o[6] = f2bf(a1.z); o[7] = f2bf(a1.w);
      *reinterpret_cast<bf16x8*>(&Af[((mf_s * 16 + k32) * 64 + l) * 8]) = o;
    }
  }
  __syncthreads();

  // ---- MFMA: 4 mf x 4 nf, k32 = 0..15, Up double-buffered prefetch ----
  f32x4 acc[4][4];
#pragma unroll
  for (int mf = 0; mf < 4; ++mf)
#pragma unroll
    for (int nf = 0; nf < 4; ++nf) acc[mf][nf] = (f32x4)0.f;

  const short* upw = Up + ((size_t)(w * 4) * 16) * 64 * 8;  // n16 base = w*4
  bf16x8 bA[4], bB[4];
#pragma unroll
  for (int nf = 0; nf < 4; ++nf)
    bA[nf] = *reinterpret_cast<const bf16x8*>(
        Up + ((size_t)((w * 4 + nf) * 16 + 0) * 64 + l) * 8);
  (void)upw;

#pragma unroll
  for (int kk = 0; kk < 8; ++kk) {
    const int k0 = 2 * kk;
    // prefetch k0+1 into bB
#pragma unroll
    for (int nf = 0; nf < 4; ++nf)
      bB[nf] = *reinterpret_cast<const bf16x8*>(
          Up + ((size_t)((w * 4 + nf) * 16 + k0 + 1) * 64 + l) * 8);
#pragma unroll
    for (int mf = 0; mf < 4; ++mf) {
      bf16x8 af = *reinterpret_cast<const bf16x8*>(
          &Af[((mf * 16 + k0) * 64 + l) * 8]);
#pragma unroll
      for (int nf = 0; nf < 4; ++nf)
        acc[mf][nf] = __builtin_amdgcn_mfma_f32_16x16x32_bf16(
            af, bA[nf], acc[mf][nf], 0, 0, 0);
    }
    // prefetch k0+2 into bA
    if (kk < 7) {
#pragma unroll
      for (int nf = 0; nf < 4; ++nf)
        bA[nf] = *reinterpret_cast<const bf16x8*>(
            Up + ((size_t)((w * 4 + nf) * 16 + k0 + 2) * 64 + l) * 8);
    }
#pragma unroll
    for (int mf = 0; mf < 4; ++mf) {
      bf16x8 af = *reinterpret_cast<const bf16x8*>(
          &Af[((mf * 16 + k0 + 1) * 64 + l) * 8]);
#pragma unroll
      for (int nf = 0; nf < 4; ++nf)
        acc[mf][nf] = __builtin_amdgcn_mfma_f32_16x16x32_bf16(
            af, bB[nf], acc[mf][nf], 0, 0, 0);
    }
  }

  // ---- scores epilogue: tanh(acc + hw[u]) * Va[u], reduce over u ----
  const float* hwb = hw + b * UU;
  float part[4][4];
#pragma unroll
  for (int mf = 0; mf < 4; ++mf)
#pragma unroll
    for (int r = 0; r < 4; ++r) part[mf][r] = 0.f;
#pragma unroll
  for (int nf = 0; nf < 4; ++nf) {
    const int u = w * 64 + nf * 16 + lo;
    const float hv = hwb[u];
    const float vv = Va[u];
#pragma unroll
    for (int mf = 0; mf < 4; ++mf)
#pragma unroll
      for (int r = 0; r < 4; ++r)
        part[mf][r] += tanh_fast(acc[mf][nf][r] + hv) * vv;
  }
#pragma unroll
  for (int mf = 0; mf < 4; ++mf)
#pragma unroll
    for (int r = 0; r < 4; ++r) {
      float s = part[mf][r];
      s += __shfl_xor(s, 1);
      s += __shfl_xor(s, 2);
      s += __shfl_xor(s, 4);
      s += __shfl_xor(s, 8);
      part[mf][r] = s;
    }
  if (lo == 0) {
#pragma unroll
    for (int mf = 0; mf < 4; ++mf)
#pragma unroll
      for (int r = 0; r < 4; ++r)
        red[w][mf * 16 + g * 4 + r] = part[mf][r];
  }
  __syncthreads();

  // ---- tile softmax stats (first 64 threads): m, e_t, l ----
  if (tid < 64) {
    float s = red[0][tid] + red[1][tid] + red[2][tid] + red[3][tid] +
              red[4][tid] + red[5][tid] + red[6][tid] + red[7][tid];
    float m = s;
#pragma unroll
    for (int off = 1; off < 64; off <<= 1) m = fmaxf(m, __shfl_xor(m, off));
    float e = __expf(s - m);
    float ls = e;
#pragma unroll
    for (int off = 1; off < 64; off <<= 1) ls += __shfl_xor(ls, off);
    e_all[tid] = e;
    if (tid == 0) {
      mbuf[b * 32 + tile] = m;
      lbuf[b * 32 + tile] = ls;
    }
  }
  __syncthreads();

  // ---- partial context: thread owns col f = tid; lane-staggered t ----
  {
    const int f = tid;               // 0..511
    const int kk2 = f >> 5;          // k32
    const int q = (f >> 2) & 3;      // g
    const int ib = (f & 3) + 4 * ((f >> 4) & 1);
    float a = 0.f;
    for (int it = 0; it < 64; ++it) {
      const int t = (it + tid) & 63;
      const int idx = (((t >> 4) * 16 + kk2) * 64 + q * 16 + (t & 15)) * 8 + ib;
      unsigned short vv = *reinterpret_cast<const unsigned short*>(&Af[idx]);
      a += e_all[t] * __uint_as_float(((unsigned)vv) << 16);
    }
    cpart[(size_t)(b * 32 + tile) * 512 + f] = a;
  }
}

// Combine tile partials: c[b][f] = sum_i w_i*cpart_i[f] / sum_i w_i*l_i.
__global__ __launch_bounds__(256) void k6_combine(
    const float* __restrict__ mbuf, const float* __restrict__ lbuf,
    const float* __restrict__ cpart, float* __restrict__ c) {
  const int b = blockIdx.x;
  const int tid = threadIdx.x;
  __shared__ float sm[32], sl[32];
  if (tid < 32) {
    sm[tid] = mbuf[b * 32 + tid];
    sl[tid] = lbuf[b * 32 + tid];
  }
  __syncthreads();
  float M = -1e30f;
#pragma unroll
  for (int i = 0; i < 32; ++i) M = fmaxf(M, sm[i]);
  float D = 0.f;
#pragma unroll
  for (int i = 0; i < 32; ++i) D += __expf(sm[i] - M) * sl[i];
  const float inv = 1.f / D;
  const int f = tid * 2;
  float a0 = 0.f, a1 = 0.f;
  for (int i = 0; i < 32; ++i) {
    const float wi = __expf(sm[i] - M);
    const float2 v = *reinterpret_cast<const float2*>(
        &cpart[(size_t)(b * 32 + i) * 512 + f]);
    a0 += wi * v.x;
    a1 += wi * v.y;
  }
  c[b * FF + f]     = a0 * inv;
  c[b * FF + f + 1] = a1 * inv;
}

// --- gate GEMMs, LDS-tiled, split-K x8 ------------------------------------
__global__ __launch_bounds__(512) void k5a_gates(
    const float* __restrict__ x, const float* __restrict__ cc,
    const float* __restrict__ h, const float* __restrict__ kern,
    const float* __restrict__ ak, const float* __restrict__ rk,
    float* __restrict__ G) {
  __shared__ float wsx[64][64], wsa[64][64], wsr[64][64];
  __shared__ float xs[32][64], cs[32][64], hs[32][64];
  const int n0 = blockIdx.x * 64;
  const int kg0 = blockIdx.y * 64;
  const bool has_r = (n0 < 1024);
  const int tid = threadIdx.x;
  const int n = tid & 63;
  const int b0 = (tid >> 6) * 4;
  const int wrow = tid >> 3, wcol = (tid & 7) * 8;
  const int orow = tid >> 4, ocol = (tid & 15) * 4;
  float acc[4] = {0.f, 0.f, 0.f, 0.f};

  {
    const size_t wb = (size_t)(kg0 + wrow) * 1536 + n0 + wcol;
    *reinterpret_cast<float4*>(&wsx[wrow][wcol])     = *reinterpret_cast<const float4*>(kern + wb);
    *reinterpret_cast<float4*>(&wsx[wrow][wcol + 4]) = *reinterpret_cast<const float4*>(kern + wb + 4);
    *reinterpret_cast<float4*>(&wsa[wrow][wcol])     = *reinterpret_cast<const float4*>(ak + wb);
    *reinterpret_cast<float4*>(&wsa[wrow][wcol + 4]) = *reinterpret_cast<const float4*>(ak + wb + 4);
    if (has_r) {
      *reinterpret_cast<float4*>(&wsr[wrow][wcol])     = *reinterpret_cast<const float4*>(rk + wb);
      *reinterpret_cast<float4*>(&wsr[wrow][wcol + 4]) = *reinterpret_cast<const float4*>(rk + wb + 4);
    }
    *reinterpret_cast<float4*>(&xs[orow][ocol]) =
        *reinterpret_cast<const float4*>(x + orow * FF + kg0 + ocol);
    *reinterpret_cast<float4*>(&cs[orow][ocol]) =
        *reinterpret_cast<const float4*>(cc + orow * FF + kg0 + ocol);
    *reinterpret_cast<float4*>(&hs[orow][ocol]) =
        *reinterpret_cast<const float4*>(h + orow * UU + kg0 + ocol);
  }
  __syncthreads();
  if (has_r) {
#pragma unroll 8
    for (int k = 0; k < 64; ++k) {
      const float wx = wsx[k][n], wa = wsa[k][n], wr = wsr[k][n];
#pragma unroll
      for (int j = 0; j < 4; ++j)
        acc[j] += xs[b0 + j][k] * wx + cs[b0 + j][k] * wa + hs[b0 + j][k] * wr;
    }
  } else {
#pragma unroll 8
    for (int k = 0; k < 64; ++k) {
      const float wx = wsx[k][n], wa = wsa[k][n];
#pragma unroll
      for (int j = 0; j < 4; ++j)
        acc[j] += xs[b0 + j][k] * wx + cs[b0 + j][k] * wa;
    }
  }
#pragma unroll
  for (int j = 0; j < 4; ++j)
    atomicAdd(&G[(size_t)(b0 + j) * 1536 + n0 + n], acc[j]);
}

__global__ __launch_bounds__(256) void k5b_zr(
    const float* __restrict__ G, const float* __restrict__ h,
    const float* __restrict__ bias, const float* __restrict__ abias,
    float* __restrict__ zs, float* __restrict__ rh) {
  int idx = blockIdx.x * blockDim.x + threadIdx.x;  // 16384
  int b = idx >> 9;
  int u = idx & 511;
  float z = 0.2f * (G[(size_t)b * 1536 + u] + bias[u] + abias[u]) + 0.5f;
  z = fminf(fmaxf(z, 0.f), 1.f);
  float r = 0.2f * (G[(size_t)b * 1536 + 512 + u] + bias[512 + u] + abias[512 + u]) + 0.5f;
  r = fminf(fmaxf(r, 0.f), 1.f);
  zs[idx] = z;
  rh[idx] = r * h[idx];
}

__global__ __launch_bounds__(512) void k5c_q(
    const float* __restrict__ rh, const float* __restrict__ rk,
    float* __restrict__ qbuf) {
  __shared__ float wsr[64][64];
  __shared__ float rs[32][64];
  const int n0 = blockIdx.x * 64;
  const int kg0 = blockIdx.y * 64;
  const int tid = threadIdx.x;
  const int n = tid & 63;
  const int b0 = (tid >> 6) * 4;
  const int wrow = tid >> 3, wcol = (tid & 7) * 8;
  const int orow = tid >> 4, ocol = (tid & 15) * 4;
  float acc[4] = {0.f, 0.f, 0.f, 0.f};

  {
    const size_t wb = (size_t)(kg0 + wrow) * 1536 + 1024 + n0 + wcol;
    *reinterpret_cast<float4*>(&wsr[wrow][wcol])     = *reinterpret_cast<const float4*>(rk + wb);
    *reinterpret_cast<float4*>(&wsr[wrow][wcol + 4]) = *reinterpret_cast<const float4*>(rk + wb + 4);
    *reinterpret_cast<float4*>(&rs[orow][ocol]) =
        *reinterpret_cast<const float4*>(rh + orow * UU + kg0 + ocol);
  }
  __syncthreads();
#pragma unroll 8
  for (int k = 0; k < 64; ++k) {
    const float w = wsr[k][n];
#pragma unroll
    for (int j = 0; j < 4; ++j) acc[j] += rs[b0 + j][k] * w;
  }
#pragma unroll
  for (int j = 0; j < 4; ++j)
    atomicAdd(&qbuf[(b0 + j) * UU + n0 + n], acc[j]);
}

__global__ __launch_bounds__(256) void k5d_out(
    const float* __restrict__ G, const float* __restrict__ qbuf,
    const float* __restrict__ zs, const float* __restrict__ h,
    const float* __restrict__ bias, const float* __restrict__ abias,
    float* __restrict__ out) {
  int idx = blockIdx.x * blockDim.x + threadIdx.x;  // 16384
  int b = idx >> 9;
  int u = idx & 511;
  float hh = tanhf(G[(size_t)b * 1536 + 1024 + u] + bias[1024 + u] +
                   abias[1024 + u] + qbuf[idx]);
  float z = zs[idx];
  out[idx] = z * h[idx] + (1.f - z) * hh;
}

extern "C" void kernel_launch(void* const* d_in, const int* in_sizes, int n_in,
                              void* d_out, int out_size, void* d_ws, size_t ws_size,
                              hipStream_t stream) {
  const float* x       = (const float*)d_in[0];
  const float* h       = (const float*)d_in[1];
  const float* ann     = (const float*)d_in[2];
  const float* kern    = (const float*)d_in[3];
  const float* rk      = (const float*)d_in[4];
  const float* ak      = (const float*)d_in[5];
  const float* Wa      = (const float*)d_in[6];
  const float* Ua      = (const float*)d_in[7];
  const float* Va      = (const float*)d_in[8];
  const float* bias    = (const float*)d_in[9];
  const float* abias   = (const float*)d_in[10];
  const float* Wa_bias = (const float*)d_in[11];
  const float* Ua_bias = (const float*)d_in[12];

  float* ws     = (float*)d_ws;
  float* hw     = ws;            // 16384
  float* mbuf   = ws + 16384;    // 1024
  float* lbuf   = ws + 17408;    // 1024
  float* cpart  = ws + 18432;    // 524288
  float* c      = ws + 542720;   // 16384
  float* G      = ws + 559104;   // 49152
  float* qbuf   = ws + 608256;   // 16384
  float* zs     = ws + 624640;   // 16384
  float* rh     = ws + 641024;   // 16384
  short* Up     = (short*)(ws + 657408);  // 262144 shorts

  // zero atomic targets G + qbuf (contiguous 65536 floats)
  hipMemsetAsync(G, 0, 65536 * sizeof(float), stream);

  dim3 g0(32, 16);
  k0_pack<<<g0, 64, 0, stream>>>(Ua, Up);

  k1_hw<<<64, 256, 0, stream>>>(h, Wa, Wa_bias, Ua_bias, hw);

  dim3 g2(TT / 64, BB);
  k2_flash<<<g2, 512, 0, stream>>>(ann, Up, Va, hw, mbuf, lbuf, cpart);

  k6_combine<<<BB, 256, 0, stream>>>(mbuf, lbuf, cpart, c);

  dim3 g5a(24, 8);
  k5a_gates<<<g5a, 512, 0, stream>>>(x, c, h, kern, ak, rk, G);

  k5b_zr<<<64, 256, 0, stream>>>(G, h, bias, abias, zs, rh);

  dim3 g5c(8, 8);
  k5c_q<<<g5c, 512, 0, stream>>>(rh, rk, qbuf);

  k5d_out<<<64, 256, 0, stream>>>(G, qbuf, zs, h, bias, abias, (float*)d_out);
}